// Round 2
// baseline (64.542 us; speedup 1.0000x reference)
//
#include <hip/hip_runtime.h>
#include <math.h>

// Quantum autoencoder forward, fully register-resident:
//   - only the 10-qubit register matters (wires 10..13 stay |0>); swap test vs
//     |000> collapses to P(aux=1) = 0.5*(1 - sum_{trash=000} |psi|^2).
//   - 1024 complex amplitudes = 64 lanes x 16 complex regs. ONE WAVE per
//     sample -> zero __syncthreads. Index i = (lane<<4) | r:
//     lane bits = wires 0..5 (MSBs), reg bits = wires 6..9 (LSBs).
//   - RX on wires 6..9: in-register pair update.
//   - RX on wires 0..5: partner via __shfl_xor (no barrier).
//   - CNOT ring = linear bit permutation -> one LDS scatter/gather per layer;
//     single-wave DS ops are in-order so no barrier. XOR-swizzled slots to
//     spread the gather across bank pairs.
//   - gate cos/sin: lane t computes gate t once; broadcast via v_readlane.

#define NQ     10
#define NDEPTH 4
#define NGATE  (NQ + NDEPTH * NQ)   // 50

// inverse of the CNOT-ring basis permutation (GF(2)-linear).
// forward: for w=0..9 sequentially, bit_{(w+1)%10} ^= bit_w  (wire w at bitpos 9-w)
__device__ inline int cnot_ring_inv(int i) {
#pragma unroll
    for (int w = NQ - 1; w >= 0; --w) {
        int cb   = (i >> (NQ - 1 - w)) & 1;
        int tpos = NQ - 1 - ((w + 1) % NQ);
        i ^= cb << tpos;
    }
    return i;
}

__device__ inline float readlane_f(float v, int lane) {
    return __int_as_float(__builtin_amdgcn_readlane(__float_as_int(v), lane));
}

__global__ __launch_bounds__(64) void qae_kernel(
    const float* __restrict__ features,   // [B, 10]
    const float* __restrict__ weights,    // [4, 10] flat
    float* __restrict__ out)              // [B]
{
    __shared__ float2 amp[1024];          // 8 KB scratch for the CNOT permutation

    const int b    = blockIdx.x;
    const int lane = threadIdx.x;         // 0..63, one wave

    // ---- lane t stashes cos/sin of gate t (t < 50) ----
    float cg = 1.0f, sg = 0.0f;
    if (lane < NGATE) {
        float ang = (lane < NQ) ? features[b * NQ + lane] : weights[lane - NQ];
        float h = 0.5f * ang;
        cg = cosf(h);
        sg = sinf(h);
    }

    // ---- state |0...0>: amplitude (lane,r)=(0,0) is 1 ----
    float re[16], im[16];
#pragma unroll
    for (int r = 0; r < 16; ++r) { re[r] = 0.0f; im[r] = 0.0f; }
    if (lane == 0) re[0] = 1.0f;

    const int base_inv = cnot_ring_inv(lane << 4);  // loop-invariant (linearity)

    // RX = [[c, -i s], [-i s, c]]: new_a = c*a + s*(i_partner_im, -partner_re)
    auto rx_lane = [&](int xmask, float c, float s) {
#pragma unroll
        for (int r = 0; r < 16; ++r) {
            float pre = __shfl_xor(re[r], xmask, 64);
            float pim = __shfl_xor(im[r], xmask, 64);
            re[r] = fmaf(c, re[r],  s * pim);
            im[r] = fmaf(c, im[r], -s * pre);
        }
    };
    auto rx_reg = [&](int mask, float c, float s) {
#pragma unroll
        for (int r = 0; r < 16; ++r) {
            if (!(r & mask)) {
                int r1 = r | mask;
                float a0r = re[r],  a0i = im[r];
                float a1r = re[r1], a1i = im[r1];
                re[r]  = fmaf(c, a0r,  s * a1i);
                im[r]  = fmaf(c, a0i, -s * a1r);
                re[r1] = fmaf(c, a1r,  s * a0i);
                im[r1] = fmaf(c, a1i, -s * a0r);
            }
        }
    };
    auto rx = [&](int w, int g) {
        float c = readlane_f(cg, g);
        float s = readlane_f(sg, g);
        if (w < 6) rx_lane(1 << (5 - w), c, s);     // lane bit
        else       rx_reg(1 << (9 - w), c, s);      // register bit
    };

    auto cnot_ring = [&]() {
        // scatter (swizzled): slot(i) = i ^ ((i>>4)&15)
#pragma unroll
        for (int r = 0; r < 16; ++r) {
            int i  = (lane << 4) | r;
            int sl = i ^ (lane & 15);
            amp[sl] = make_float2(re[r], im[r]);
        }
        // gather: new[j] = old[perm_inv(j)]; single-wave DS ops are in-order
#pragma unroll
        for (int r = 0; r < 16; ++r) {
            int src = base_inv ^ cnot_ring_inv(r);  // inv(r) folds to a constant
            int sl  = src ^ ((src >> 4) & 15);
            float2 v = amp[sl];
            re[r] = v.x;
            im[r] = v.y;
        }
    };

    // ---- AngleEmbedding ----
#pragma unroll
    for (int w = 0; w < NQ; ++w) rx(w, w);

    // ---- BasicEntanglerLayers ----
    for (int l = 0; l < NDEPTH; ++l) {
#pragma unroll
        for (int w = 0; w < NQ; ++w) rx(w, NQ + l * NQ + w);
        cnot_ring();
    }

    // ---- swap test (analytic): trash bits are reg bits 2..0 -> r in {0, 8} ----
    float acc = re[0]*re[0] + im[0]*im[0] + re[8]*re[8] + im[8]*im[8];
#pragma unroll
    for (int off = 32; off; off >>= 1)
        acc += __shfl_xor(acc, off, 64);
    if (lane == 0)
        out[b] = 0.5f * (1.0f - acc);
}

extern "C" void kernel_launch(void* const* d_in, const int* in_sizes, int n_in,
                              void* d_out, int out_size, void* d_ws, size_t ws_size,
                              hipStream_t stream) {
    const float* features = (const float*)d_in[0];   // [B,10] float32
    const float* weights  = (const float*)d_in[1];   // [4,10] float32
    float*       out      = (float*)d_out;           // [B] float32

    int B = in_sizes[0] / NQ;                        // 256
    qae_kernel<<<B, 64, 0, stream>>>(features, weights, out);
}